// Round 16
// baseline (1084.085 us; speedup 1.0000x reference)
//
#include <hip/hip_runtime.h>
#include <hip/hip_bf16.h>
#include <math.h>

typedef __bf16 bf16_t;
typedef __bf16 bf16x8 __attribute__((ext_vector_type(8)));
typedef float  f32x4 __attribute__((ext_vector_type(4)));
typedef float  f4    __attribute__((ext_vector_type(4)));
typedef float  f2    __attribute__((ext_vector_type(2)));
typedef unsigned short u16x4 __attribute__((ext_vector_type(4)));
typedef unsigned long long u64;

#define HS  512
#define BB  128
#define TT  40
#define VV  10000
#define VGGN 4096
#define SLOT ((size_t)65536)   // 128*512
#define NBLK 48                // persistent recurrence blocks (16 L0 + 32 L1)
#define NGRID 256              // total blocks (48 persist + 208 logits workers)

// Per-slot counter lines (u32 index into sync; 64 u32 = 256B per line):
#define CRH0(s) ((s) * 64)
#define CHB0(s) ((41 + (s)) * 64)
#define CRH1(s) ((82 + (s)) * 64)
#define CHB1(s) ((123 + (s)) * 64)
#define NSYNCW (164 * 64)

// ============================================================================
// Data-plane protocol (validated R12-R14): cross-block buffers are WRITE-ONCE
// slots; producers use agent-scope (L2-bypass) stores so L3 is current;
// consumers use PLAIN cached loads (demand-fetch strictly after the slot's
// counter reaches its producer count; entry __threadfence kills stale clean
// lines from ws-poison/prior replays). u/h state lives in registers
// (column-ownership, R14). R15/16: global lockstep replaced by per-slot
// producer counters — each consumer waits only on its true dependencies.
// ============================================================================
__device__ __forceinline__ void cst64(void* p, u64 v) {
  __hip_atomic_store((u64*)p, v, __ATOMIC_RELAXED, __HIP_MEMORY_SCOPE_AGENT);
}

// Producer: all waves' agent stores drained (vmcnt(0) before s_barrier), then
// thread0 bumps the slot counter.
__device__ __forceinline__ void slot_inc(unsigned* sync, int line)
{
  __syncthreads();
  asm volatile("" ::: "memory");
  if (threadIdx.x == 0)
    __hip_atomic_fetch_add(&sync[line], 1u, __ATOMIC_RELAXED,
                           __HIP_MEMORY_SCOPE_AGENT);
}

// Consumer: poll until counter reaches target. SLP is a compile-time literal
// (s_sleep requires a constant immediate).
template<int SLP>
__device__ __forceinline__ void slot_wait(unsigned* sync, int line,
                                          unsigned target)
{
  if (threadIdx.x == 0) {
    while (__hip_atomic_load(&sync[line], __ATOMIC_RELAXED,
                             __HIP_MEMORY_SCOPE_AGENT) < target)
      __builtin_amdgcn_s_sleep(SLP);
  }
  asm volatile("" ::: "memory");
  __syncthreads();
}

__device__ __forceinline__ void slot_wait2(unsigned* sync, int lineA,
                                           unsigned tA, int lineB, unsigned tB)
{
  if (threadIdx.x == 0) {
    while (__hip_atomic_load(&sync[lineA], __ATOMIC_RELAXED,
                             __HIP_MEMORY_SCOPE_AGENT) < tA)
      __builtin_amdgcn_s_sleep(8);
    while (__hip_atomic_load(&sync[lineB], __ATOMIC_RELAXED,
                             __HIP_MEMORY_SCOPE_AGENT) < tB)
      __builtin_amdgcn_s_sleep(8);
  }
  asm volatile("" ::: "memory");
  __syncthreads();
}

__global__ void zero_sync(unsigned* p)
{
  for (int i = threadIdx.x; i < NSYNCW; i += 256) p[i] = 0u;
}

// ============================================================================
// Batched MFMA GEMM: C[M,N] = A[M,512] @ Bt[N,512]^T (+bias), fp32 out.
// (used for the xg0 pass)
// ============================================================================
__global__ __launch_bounds__(256) void gemm_bt(
    const bf16_t* __restrict__ A, const bf16_t* __restrict__ Bt,
    const float* __restrict__ bias, float* __restrict__ C,
    int Nvalid, int ldc, int permute_tb)
{
  const int bm = blockIdx.x * 128, bn = blockIdx.y * 128;
  const int tid = threadIdx.x;
  const int wave = tid >> 6, lane = tid & 63;
  const int wm = (wave >> 1) * 64, wn = (wave & 1) * 64;
  const int l15 = lane & 15, kg = lane >> 4;
  const bf16_t* Ap = A + (size_t)(bm + wm + l15) * 512 + kg * 8;
  const bf16_t* Bp = Bt + (size_t)(bn + wn + l15) * 512 + kg * 8;
  f32x4 acc[4][4];
#pragma unroll
  for (int i = 0; i < 4; ++i)
#pragma unroll
    for (int j = 0; j < 4; ++j)
#pragma unroll
      for (int e = 0; e < 4; ++e) acc[i][j][e] = 0.f;

  for (int kk = 0; kk < 512; kk += 32) {
    bf16x8 a[4], b[4];
#pragma unroll
    for (int i = 0; i < 4; ++i) a[i] = *(const bf16x8*)(Ap + (size_t)i * 16 * 512 + kk);
#pragma unroll
    for (int j = 0; j < 4; ++j) b[j] = *(const bf16x8*)(Bp + (size_t)j * 16 * 512 + kk);
#pragma unroll
    for (int i = 0; i < 4; ++i)
#pragma unroll
      for (int j = 0; j < 4; ++j)
        acc[i][j] = __builtin_amdgcn_mfma_f32_16x16x32_bf16(a[i], b[j], acc[i][j], 0, 0, 0);
  }

#pragma unroll
  for (int fm = 0; fm < 4; ++fm) {
#pragma unroll
    for (int fn = 0; fn < 4; ++fn) {
      int n = bn + wn + fn * 16 + l15;
      if (n >= Nvalid) continue;
      float bv = bias ? bias[n] : 0.f;
#pragma unroll
      for (int e = 0; e < 4; ++e) {
        int m = bm + wm + fm * 16 + kg * 4 + e;
        int orow = permute_tb ? ((m & 127) * TT + (m >> 7)) : m;
        C[(size_t)orow * ldc + n] = acc[fm][fn][e] + bv;
      }
    }
  }
}

// ============================================================================
// Column-ownership persistent GRU + fused logits, dataflow-synced:
//   blocks [0,16):  layer 0, block q owns H-cols [q*32, q*32+32)
//   blocks [16,48): layer 1, block q owns H-cols [q*16, q*16+16)
//   blocks [48,256): logits workers (consume hb1 slots via CHB1 counters)
// L0 loop (s=0..39): [wait CHB0(s)=16 if s>0] RU0 -> inc CRH0(s) ;
//                    wait CRH0(s)=16 ; C0 -> inc CHB0(s+1).
// L1 loop (s=1..40): wait CHB0(s)=16 [+ CHB1(s-1)=32 if s>1] ; RU1 ->
//                    inc CRH1(s) ; wait CRH1(s)=32 ; C1 -> inc CHB1(s).
// Layers free-run as a pipeline; no global lockstep.
// ============================================================================
struct PArgs {
  const bf16_t *Btru0, *Bt1ru, *Btc0, *Btc1;
  const float  *xg0, *bu, *br, *bc, *hs0init;
  bf16_t *hb0_seq, *hb1_seq, *rh0s, *rh1s;
  const bf16_t *Wto;
  const float  *bo;
  float *out, *out_hfin;
  unsigned *sync;
};

template<int K, int NF>
__device__ __forceinline__ void tile_gemm(
    const bf16_t* __restrict__ A0, const bf16_t* __restrict__ A1,
    const bf16_t* Bs, int wave, int lane, f32x4 (&acc)[2][4])
{
  const int l15 = lane & 15, kg = lane >> 4;
  const int mw = wave * 32;
#pragma unroll
  for (int i = 0; i < 2; ++i)
#pragma unroll
    for (int f = 0; f < NF; ++f)
#pragma unroll
      for (int e = 0; e < 4; ++e) acc[i][f][e] = 0.f;

#pragma unroll
  for (int kk = 0; kk < K; kk += 32) {
    const bf16_t* Asrc = (kk < 512) ? A0 : A1;
    const int kc = (kk < 512 ? kk : kk - 512) + kg * 8;
    bf16x8 a[2];
#pragma unroll
    for (int i = 0; i < 2; ++i)
      a[i] = *(const bf16x8*)(Asrc + (size_t)(mw + i * 16 + l15) * 512 + kc);
    bf16x8 b[NF];
#pragma unroll
    for (int f = 0; f < NF; ++f) {
      int row = f * 16 + l15;
      int byteoff = row * (2 * K) + ((2 * kk + 16 * kg) ^ ((row & 7) << 4));
      b[f] = *(const bf16x8*)((const char*)Bs + byteoff);
    }
#pragma unroll
    for (int i = 0; i < 2; ++i)
#pragma unroll
      for (int f = 0; f < NF; ++f)
        acc[i][f] = __builtin_amdgcn_mfma_f32_16x16x32_bf16(a[i], b[f], acc[i][f], 0, 0, 0);
  }
}

// Publish C cols (32 or 16) of a 128-row fragment set as bf16 into a
// row-major [128][512] slice at col n0 (fragment -> LDS transpose ->
// coalesced agent u64 stores).
template<int C>
__device__ __forceinline__ void publish(
    bf16_t* dst, int n0, float (&v)[2][2][4],
    unsigned short (*tb)[36], int wave, int lane, int tid)
{
  const int l15 = lane & 15, kg = lane >> 4;
  const int mw = wave * 32;
  constexpr int NFp = C / 16;
#pragma unroll
  for (int i = 0; i < 2; ++i)
#pragma unroll
    for (int f = 0; f < NFp; ++f)
#pragma unroll
      for (int e = 0; e < 4; ++e)
        tb[mw + i * 16 + kg * 4 + e][f * 16 + l15] =
            __builtin_bit_cast(unsigned short, (bf16_t)v[i][f][e]);
  __syncthreads();
  constexpr int NU = 128 * C / 4;
  constexpr int IT = NU / 256;
#pragma unroll
  for (int it = 0; it < IT; ++it) {
    int lin = it * 256 + tid;
    int row = lin / (C / 4);
    int cc  = (lin % (C / 4)) * 4;
    u16x4 pk = { tb[row][cc], tb[row][cc + 1], tb[row][cc + 2], tb[row][cc + 3] };
    cst64(dst + (size_t)row * 512 + n0 + cc, __builtin_bit_cast(u64, pk));
  }
}

__global__ __launch_bounds__(256) void gru_persist(PArgs P)
{
  const int bid = blockIdx.x, tid = threadIdx.x;
  const int wave = tid >> 6, lane = tid & 63;
  const int l15 = lane & 15, kg = lane >> 4;
  const int mw = wave * 32;
  unsigned* sync = P.sync;

  // One-time per-block L2/L1 invalidate (stale clean-line protocol, R12).
  __threadfence();
  __syncthreads();

  // ===================== logits worker blocks =====================
  if (bid >= NBLK) {
    const int w = bid - NBLK;                 // 0..207
    const int wm = (wave >> 1) * 64, wn = (wave & 1) * 64;
    for (int tau = w; tau < TT * 79; tau += (NGRID - NBLK)) {
      const int t = tau / 79, nb = tau % 79;
      slot_wait<64>(sync, CHB1(t + 1), 32u);
      const bf16_t* A = P.hb1_seq + (size_t)(t + 1) * SLOT;
      const bf16_t* Bp = P.Wto + (size_t)(nb * 128 + wn + l15) * 512 + kg * 8;
      f32x4 acc[4][4];
#pragma unroll
      for (int i = 0; i < 4; ++i)
#pragma unroll
        for (int j = 0; j < 4; ++j)
#pragma unroll
          for (int e = 0; e < 4; ++e) acc[i][j][e] = 0.f;
      for (int kk = 0; kk < 512; kk += 32) {
        bf16x8 a[4], b[4];
#pragma unroll
        for (int i = 0; i < 4; ++i)
          a[i] = *(const bf16x8*)(A + (size_t)(wm + i * 16 + l15) * 512 + kk + kg * 8);
#pragma unroll
        for (int j = 0; j < 4; ++j)
          b[j] = *(const bf16x8*)(Bp + (size_t)j * 16 * 512 + kk);
#pragma unroll
        for (int i = 0; i < 4; ++i)
#pragma unroll
          for (int j = 0; j < 4; ++j)
            acc[i][j] = __builtin_amdgcn_mfma_f32_16x16x32_bf16(a[i], b[j], acc[i][j], 0, 0, 0);
      }
#pragma unroll
      for (int fm = 0; fm < 4; ++fm) {
#pragma unroll
        for (int fn = 0; fn < 4; ++fn) {
          int n = nb * 128 + wn + fn * 16 + l15;
          if (n >= VV) continue;
          float bv = P.bo[n];
#pragma unroll
          for (int e = 0; e < 4; ++e) {
            int b_row = wm + fm * 16 + kg * 4 + e;
            P.out[(size_t)(b_row * TT + t) * VV + n] = acc[fm][fn][e] + bv;
          }
        }
      }
      __syncthreads();
    }
    return;
  }

  // ===================== recurrence blocks (column-ownership) =============
  const bool L0 = (bid < 16);
  const int q  = L0 ? bid : bid - 16;
  const int n0 = L0 ? q * 32 : q * 16;

  __shared__ bf16_t Bs[49152];                  // [RU 64KB | C 32KB]
  __shared__ unsigned short tb[128][36];
  bf16_t* BsRU = Bs;
  bf16_t* BsC  = Bs + 32768;

  if (L0) {
    for (int c = tid; c < 4096; c += 256) {
      int row = c >> 6, cb = (c & 63) * 16;
      const bf16_t* src = (row < 32) ? P.Btru0 + (size_t)(n0 + row) * 512
                                     : P.Btru0 + (size_t)(512 + n0 + row - 32) * 512;
      *(f4*)((char*)BsRU + row * 1024 + (cb ^ ((row & 7) << 4))) =
          *(const f4*)((const char*)src + cb);
    }
    for (int c = tid; c < 2048; c += 256) {
      int row = c >> 6, cb = (c & 63) * 16;
      const bf16_t* src = P.Btc0 + (size_t)(n0 + row) * 512;
      *(f4*)((char*)BsC + row * 1024 + (cb ^ ((row & 7) << 4))) =
          *(const f4*)((const char*)src + cb);
    }
  } else {
    for (int c = tid; c < 4096; c += 256) {
      int row = c >> 7, cb = (c & 127) * 16;
      const bf16_t* src = (row < 16) ? P.Bt1ru + (size_t)(n0 + row) * 1024
                                     : P.Bt1ru + (size_t)(512 + n0 + row - 16) * 1024;
      *(f4*)((char*)BsRU + row * 2048 + (cb ^ ((row & 7) << 4))) =
          *(const f4*)((const char*)src + cb);
    }
    for (int c = tid; c < 2048; c += 256) {
      int row = c >> 7, cb = (c & 127) * 16;
      const bf16_t* src = P.Btc1 + (size_t)(n0 + row) * 1024;
      *(f4*)((char*)BsC + row * 2048 + (cb ^ ((row & 7) << 4))) =
          *(const f4*)((const char*)src + cb);
    }
  }
  __syncthreads();

  const int NFh = L0 ? 2 : 1;
  float hreg[2][2][4], ureg[2][2][4], rhv[2][2][4];
#pragma unroll
  for (int i = 0; i < 2; ++i)
    for (int f = 0; f < 2; ++f)
#pragma unroll
      for (int e = 0; e < 4; ++e) {
        int row = mw + i * 16 + kg * 4 + e;
        hreg[i][f][e] = (f < NFh)
            ? P.hs0init[(size_t)row * 512 + n0 + f * 16 + l15] : 0.f;
        ureg[i][f][e] = 0.f; rhv[i][f][e] = 0.f;
      }

  if (L0) {
    // ===================== layer-0 chain =====================
    for (int s = 0; s < 40; ++s) {
      if (s >= 1) slot_wait<8>(sync, CHB0(s), 16u);
      f32x4 acc[2][4];
      const bf16_t* A0 = P.hb0_seq + (size_t)s * SLOT;
      tile_gemm<512, 4>(A0, A0, BsRU, wave, lane, acc);
      const float* xg = P.xg0 + (size_t)s * 128 * 1536;
#pragma unroll
      for (int i = 0; i < 2; ++i)
#pragma unroll
        for (int f = 0; f < 2; ++f)
#pragma unroll
          for (int e = 0; e < 4; ++e) {
            int row = mw + i * 16 + kg * 4 + e;
            int col = n0 + f * 16 + l15;
            float pu = acc[i][f][e]     + xg[(size_t)row * 1536 + col];
            float pr = acc[i][f + 2][e] + xg[(size_t)row * 1536 + 512 + col];
            ureg[i][f][e] = 1.f / (1.f + expf(-pu));
            rhv[i][f][e]  = (1.f / (1.f + expf(-pr))) * hreg[i][f][e];
          }
      publish<32>(P.rh0s + (size_t)s * SLOT, n0, rhv, tb, wave, lane, tid);
      slot_inc(sync, CRH0(s));
      slot_wait<8>(sync, CRH0(s), 16u);

      const bf16_t* Arh = P.rh0s + (size_t)s * SLOT;
      tile_gemm<512, 2>(Arh, Arh, BsC, wave, lane, acc);
#pragma unroll
      for (int i = 0; i < 2; ++i)
#pragma unroll
        for (int f = 0; f < 2; ++f)
#pragma unroll
          for (int e = 0; e < 4; ++e) {
            int row = mw + i * 16 + kg * 4 + e;
            int col = n0 + f * 16 + l15;
            float c = tanhf(acc[i][f][e] + xg[(size_t)row * 1536 + 1024 + col]);
            float u = ureg[i][f][e];
            hreg[i][f][e] = u * hreg[i][f][e] + (1.f - u) * c;
            rhv[i][f][e] = hreg[i][f][e];
          }
      publish<32>(P.hb0_seq + (size_t)(s + 1) * SLOT, n0, rhv, tb, wave, lane, tid);
      slot_inc(sync, CHB0(s + 1));
    }
  } else {
    // ===================== layer-1 chain =====================
    for (int s = 1; s <= 40; ++s) {
      if (s >= 2) slot_wait2(sync, CHB0(s), 16u, CHB1(s - 1), 32u);
      else        slot_wait<8>(sync, CHB0(s), 16u);
      f32x4 acc[2][4];
      tile_gemm<1024, 2>(P.hb0_seq + (size_t)s * SLOT,
                         P.hb1_seq + (size_t)(s - 1) * SLOT,
                         BsRU, wave, lane, acc);
      float bvu = P.bu[512 + n0 + l15];
      float bvr = P.br[512 + n0 + l15];
#pragma unroll
      for (int i = 0; i < 2; ++i)
#pragma unroll
        for (int e = 0; e < 4; ++e) {
          float pu = acc[i][0][e] + bvu;
          float pr = acc[i][1][e] + bvr;
          ureg[i][0][e] = 1.f / (1.f + expf(-pu));
          rhv[i][0][e]  = (1.f / (1.f + expf(-pr))) * hreg[i][0][e];
        }
      publish<16>(P.rh1s + (size_t)s * SLOT, n0, rhv, tb, wave, lane, tid);
      slot_inc(sync, CRH1(s));
      slot_wait<8>(sync, CRH1(s), 32u);

      tile_gemm<1024, 1>(P.hb0_seq + (size_t)s * SLOT,
                         P.rh1s + (size_t)s * SLOT,
                         BsC, wave, lane, acc);
      float bvc = P.bc[512 + n0 + l15];
#pragma unroll
      for (int i = 0; i < 2; ++i)
#pragma unroll
        for (int e = 0; e < 4; ++e) {
          float c = tanhf(acc[i][0][e] + bvc);
          float u = ureg[i][0][e];
          hreg[i][0][e] = u * hreg[i][0][e] + (1.f - u) * c;
          rhv[i][0][e] = hreg[i][0][e];
        }
      publish<16>(P.hb1_seq + (size_t)s * SLOT, n0, rhv, tb, wave, lane, tid);
      slot_inc(sync, CHB1(s));
    }
  }

  // ---- h_final [L,B,H]: owner blocks write their fp32 column slices ----
  float* dst = P.out_hfin + (L0 ? 0 : 65536);
#pragma unroll
  for (int i = 0; i < 2; ++i)
    for (int f = 0; f < NFh; ++f)
#pragma unroll
      for (int e = 0; e < 4; ++e) {
        int row = mw + i * 16 + kg * 4 + e;
        dst[(size_t)row * 512 + n0 + f * 16 + l15] = hreg[i][f][e];
      }
}

// ============================================================================
// h0 = tanh(vgg @ W_in + b_in) via bf16 MFMA, split-K=8.
// ============================================================================
__global__ __launch_bounds__(256) void h0_gemm(
    const bf16_t* __restrict__ vggb, const bf16_t* __restrict__ Wint,
    float* __restrict__ part)
{
  const int bn = blockIdx.x * 128, z = blockIdx.y, k0 = z * 512;
  const int tid = threadIdx.x;
  const int wave = tid >> 6, lane = tid & 63;
  const int wm = (wave >> 1) * 64, wn = (wave & 1) * 64;
  const int l15 = lane & 15, kg = lane >> 4;
  const bf16_t* Ap = vggb + (size_t)(wm + l15) * 4096 + k0 + kg * 8;
  const bf16_t* Bp = Wint + (size_t)(bn + wn + l15) * 4096 + k0 + kg * 8;
  f32x4 acc[4][4];
#pragma unroll
  for (int i = 0; i < 4; ++i)
#pragma unroll
    for (int j = 0; j < 4; ++j)
#pragma unroll
      for (int e = 0; e < 4; ++e) acc[i][j][e] = 0.f;
  for (int kk = 0; kk < 512; kk += 32) {
    bf16x8 a[4], b[4];
#pragma unroll
    for (int i = 0; i < 4; ++i) a[i] = *(const bf16x8*)(Ap + (size_t)i * 16 * 4096 + kk);
#pragma unroll
    for (int j = 0; j < 4; ++j) b[j] = *(const bf16x8*)(Bp + (size_t)j * 16 * 4096 + kk);
#pragma unroll
    for (int i = 0; i < 4; ++i)
#pragma unroll
      for (int j = 0; j < 4; ++j)
        acc[i][j] = __builtin_amdgcn_mfma_f32_16x16x32_bf16(a[i], b[j], acc[i][j], 0, 0, 0);
  }
#pragma unroll
  for (int fm = 0; fm < 4; ++fm)
#pragma unroll
    for (int fn = 0; fn < 4; ++fn) {
      int n = bn + wn + fn * 16 + l15;
#pragma unroll
      for (int e = 0; e < 4; ++e) {
        int m = wm + fm * 16 + kg * 4 + e;
        part[(size_t)z * SLOT + m * 512 + n] = acc[fm][fn][e];
      }
    }
}

__global__ void h0_fin(const float* __restrict__ part, const float* __restrict__ bin,
                       float* __restrict__ hs0init,
                       bf16_t* __restrict__ hb00, bf16_t* __restrict__ hb10)
{
  int i = blockIdx.x * 256 + threadIdx.x;   // 65536
  int n = i & 511;
  float s = bin[n];
#pragma unroll
  for (int z = 0; z < 8; ++z) s += part[(size_t)z * SLOT + i];
  float v = tanhf(s);
  hs0init[i] = v;
  hb00[i] = (bf16_t)v; hb10[i] = (bf16_t)v;
}

__global__ void conv_bf16(const float* __restrict__ src, bf16_t* __restrict__ dst)
{
  int i = blockIdx.x * 256 + threadIdx.x;
  f4 v = ((const f4*)src)[i];
  dst[i * 4 + 0] = (bf16_t)v[0]; dst[i * 4 + 1] = (bf16_t)v[1];
  dst[i * 4 + 2] = (bf16_t)v[2]; dst[i * 4 + 3] = (bf16_t)v[3];
}

__global__ void gather_emb(const int* __restrict__ tok, const float* __restrict__ emb,
                           bf16_t* __restrict__ A)
{
  int m = blockIdx.x;
  int t = m >> 7, b = m & 127;
  int tk = tok[b * TT + t];
  const float* src = emb + (size_t)tk * 512;
  int i = threadIdx.x;
  f4 v = *(const f4*)(src + i * 4);
  bf16_t* dst = A + (size_t)m * 512 + i * 4;
  dst[0] = (bf16_t)v[0]; dst[1] = (bf16_t)v[1];
  dst[2] = (bf16_t)v[2]; dst[3] = (bf16_t)v[3];
}

struct TJob { const float* src; bf16_t* dst; int K; int dstld; };
struct TJobs10 { TJob j[10]; };
__global__ void transpose_gen(TJobs10 jobs)
{
  TJob jb = jobs.j[blockIdx.z];
  int k0 = blockIdx.x * 32;
  if (k0 >= jb.K) return;
  int n0 = blockIdx.y * 32;
  __shared__ float tile[32][33];
  int tx = threadIdx.x, ty = threadIdx.y;
#pragma unroll
  for (int r = 0; r < 4; ++r)
    tile[ty + 8 * r][tx] = jb.src[(size_t)(k0 + ty + 8 * r) * 512 + n0 + tx];
  __syncthreads();
#pragma unroll
  for (int r = 0; r < 4; ++r)
    jb.dst[(size_t)(n0 + ty + 8 * r) * jb.dstld + k0 + tx] = (bf16_t)tile[tx][ty + 8 * r];
}

__global__ void transpose_wout(const float* __restrict__ W, bf16_t* __restrict__ dst)
{
  __shared__ float tile[32][33];
  int k0 = blockIdx.x * 32, n0 = blockIdx.y * 32;
  int tx = threadIdx.x, ty = threadIdx.y;
#pragma unroll
  for (int r = 0; r < 4; ++r) {
    int n = n0 + tx;
    tile[ty + 8 * r][tx] = (n < VV) ? W[(size_t)(k0 + ty + 8 * r) * VV + n] : 0.f;
  }
  __syncthreads();
#pragma unroll
  for (int r = 0; r < 4; ++r)
    dst[(size_t)(n0 + ty + 8 * r) * 512 + k0 + tx] = (bf16_t)tile[tx][ty + 8 * r];
}

__global__ void build_xbias(const float* __restrict__ bu, const float* __restrict__ br,
                            const float* __restrict__ bc, float* __restrict__ xb)
{
  int i = blockIdx.x * 256 + threadIdx.x;
  if (i < 2 * 1536) {
    int j = i / 1536, qq = i % 1536;
    int g = qq >> 9, n = qq & 511;
    const float* src = (g == 0) ? bu : (g == 1) ? br : bc;
    xb[i] = src[j * 512 + n];
  }
}

// ============================================================================
extern "C" void kernel_launch(void* const* d_in, const int* in_sizes, int n_in,
                              void* d_out, int out_size, void* d_ws, size_t ws_size,
                              hipStream_t stream)
{
  const int*   tok = (const int*)  d_in[0];
  const float* vgg = (const float*)d_in[1];
  const float* emb = (const float*)d_in[2];
  const float* Win = (const float*)d_in[3];
  const float* bin = (const float*)d_in[4];
  const float* Wu  = (const float*)d_in[5];
  const float* bu  = (const float*)d_in[6];
  const float* Wr  = (const float*)d_in[7];
  const float* br  = (const float*)d_in[8];
  const float* Wc  = (const float*)d_in[9];
  const float* bc  = (const float*)d_in[10];
  const float* Wo  = (const float*)d_in[11];
  const float* bo  = (const float*)d_in[12];
  float* out = (float*)d_out;

  size_t off = 0;
  auto alloc = [&](size_t bytes) -> void* {
    void* p = (char*)d_ws + off;
    off += (bytes + 255) & ~(size_t)255;
    return p;
  };
  float*  hs0init = (float*) alloc(SLOT * 4);
  bf16_t* rh0s  = (bf16_t*)alloc(41 * SLOT * 2);
  bf16_t* rh1s  = (bf16_t*)alloc(41 * SLOT * 2);
  bf16_t* hb0_seq = (bf16_t*)alloc(41 * SLOT * 2);
  bf16_t* hb1_seq = (bf16_t*)alloc(41 * SLOT * 2);
  bf16_t* Aemb  = (bf16_t*)alloc((size_t)TT * BB * 512 * 2);
  float*  xg0   = (float*) alloc((size_t)TT * BB * 1536 * 4);
  bf16_t* Btx0  = (bf16_t*)alloc((size_t)1536 * 512 * 2);
  bf16_t* Btru0 = (bf16_t*)alloc((size_t)1024 * 512 * 2);
  bf16_t* Btc0  = (bf16_t*)alloc((size_t)512 * 512 * 2);
  bf16_t* Bt1ru = (bf16_t*)alloc((size_t)1024 * 1024 * 2);
  bf16_t* Btc1  = (bf16_t*)alloc((size_t)512 * 1024 * 2);
  bf16_t* Wto   = (bf16_t*)alloc((size_t)10112 * 512 * 2);
  bf16_t* Wint  = (bf16_t*)alloc((size_t)512 * 4096 * 2);
  bf16_t* vggb  = (bf16_t*)alloc((size_t)128 * 4096 * 2);
  float*  h0part= (float*) alloc(8 * SLOT * 4);
  float*  xbias = (float*) alloc(2 * 1536 * 4);
  unsigned* syncws = (unsigned*) alloc(NSYNCW * 4);
  if (off > ws_size) return;

  TJobs10 tj;
  tj.j[0] = { Wu,                Btx0,                512, 512 };
  tj.j[1] = { Wr,                Btx0 + 262144,       512, 512 };
  tj.j[2] = { Wc,                Btx0 + 524288,       512, 512 };
  tj.j[3] = { Wu + 262144,       Btru0,               512, 512 };
  tj.j[4] = { Wr + 262144,       Btru0 + 262144,      512, 512 };
  tj.j[5] = { Wc + 262144,       Btc0,                512, 512 };
  tj.j[6] = { Wu + 524288,       Bt1ru,               1024, 1024 };
  tj.j[7] = { Wr + 524288,       Bt1ru + 524288,      1024, 1024 };
  tj.j[8] = { Wc + 524288,       Btc1,                1024, 1024 };
  tj.j[9] = { Win,               Wint,                4096, 4096 };
  transpose_gen<<<dim3(128, 16, 10), dim3(32, 8), 0, stream>>>(tj);
  transpose_wout<<<dim3(16, 316), dim3(32, 8), 0, stream>>>(Wo, Wto);
  build_xbias<<<12, 256, 0, stream>>>(bu, br, bc, xbias);
  gather_emb<<<TT * BB, 128, 0, stream>>>(tok, emb, Aemb);
  conv_bf16<<<512, 256, 0, stream>>>(vgg, vggb);
  zero_sync<<<1, 256, 0, stream>>>(syncws);

  h0_gemm<<<dim3(4, 8), 256, 0, stream>>>(vggb, Wint, h0part);
  h0_fin<<<256, 256, 0, stream>>>(h0part, bin, hs0init, hb0_seq, hb1_seq);

  gemm_bt<<<dim3(40, 12), 256, 0, stream>>>(Aemb, Btx0, xbias, xg0, 1536, 1536, 0);

  PArgs pa;
  pa.Btru0 = Btru0; pa.Bt1ru = Bt1ru; pa.Btc0 = Btc0; pa.Btc1 = Btc1;
  pa.xg0 = xg0; pa.bu = bu; pa.br = br; pa.bc = bc; pa.hs0init = hs0init;
  pa.hb0_seq = hb0_seq; pa.hb1_seq = hb1_seq;
  pa.rh0s = rh0s; pa.rh1s = rh1s;
  pa.Wto = Wto; pa.bo = bo; pa.out = out;
  pa.out_hfin = out + (size_t)BB * TT * VV;
  pa.sync = syncws;
  gru_persist<<<NGRID, 256, 0, stream>>>(pa);
}

// Round 17
// 626.810 us; speedup vs baseline: 1.7295x; 1.7295x over previous
//
#include <hip/hip_runtime.h>
#include <hip/hip_bf16.h>
#include <math.h>

typedef __bf16 bf16_t;
typedef __bf16 bf16x8 __attribute__((ext_vector_type(8)));
typedef float  f32x4 __attribute__((ext_vector_type(4)));
typedef float  f4    __attribute__((ext_vector_type(4)));
typedef float  f2    __attribute__((ext_vector_type(2)));
typedef unsigned short u16x4 __attribute__((ext_vector_type(4)));
typedef unsigned long long u64;

#define HS  512
#define BB  128
#define TT  40
#define VV  10000
#define VGGN 4096
#define SLOT ((size_t)65536)   // 128*512
#define NBLK 96                // 2 pipelines x (16 L0 + 32 L1)
#define NGRID 256              // + 160 logits workers

// Per-slot counter lines, PER HALF-PIPELINE (u32 index; 64 u32 = 256B/line).
#define CL(h, idx) ((((h) * 164) + (idx)) * 64)
#define CRH0(h,s) CL(h, (s))
#define CHB0(h,s) CL(h, 41 + (s))
#define CRH1(h,s) CL(h, 82 + (s))
#define CHB1(h,s) CL(h, 123 + (s))
#define NSYNCW (328 * 64)

// ============================================================================
// Data-plane protocol (validated R12-R14): cross-block buffers are WRITE-ONCE
// slots; producers use agent-scope (L2-bypass) stores so L3 is current;
// consumers use PLAIN cached loads after the slot counter fires; entry
// __threadfence kills stale clean lines (ws-poison / prior replays).
// u/h state in registers (column-ownership, R14). R17: the batch dim is
// row-independent -> TWO free-running 64-row pipelines (halved per-link
// bandwidth & GEMM; fixed sync cost unchanged); workers join both halves.
// ============================================================================
__device__ __forceinline__ void cst64(void* p, u64 v) {
  __hip_atomic_store((u64*)p, v, __ATOMIC_RELAXED, __HIP_MEMORY_SCOPE_AGENT);
}

__device__ __forceinline__ void slot_inc(unsigned* sync, int line)
{
  __syncthreads();                 // drain agent stores (vmcnt(0) at barrier)
  asm volatile("" ::: "memory");
  if (threadIdx.x == 0)
    __hip_atomic_fetch_add(&sync[line], 1u, __ATOMIC_RELAXED,
                           __HIP_MEMORY_SCOPE_AGENT);
}

template<int SLP>
__device__ __forceinline__ void slot_wait(unsigned* sync, int line,
                                          unsigned target)
{
  if (threadIdx.x == 0) {
    while (__hip_atomic_load(&sync[line], __ATOMIC_RELAXED,
                             __HIP_MEMORY_SCOPE_AGENT) < target)
      __builtin_amdgcn_s_sleep(SLP);
  }
  asm volatile("" ::: "memory");
  __syncthreads();
}

template<int SLP>
__device__ __forceinline__ void slot_wait2(unsigned* sync, int lineA,
                                           unsigned tA, int lineB, unsigned tB)
{
  if (threadIdx.x == 0) {
    while (__hip_atomic_load(&sync[lineA], __ATOMIC_RELAXED,
                             __HIP_MEMORY_SCOPE_AGENT) < tA)
      __builtin_amdgcn_s_sleep(SLP);
    while (__hip_atomic_load(&sync[lineB], __ATOMIC_RELAXED,
                             __HIP_MEMORY_SCOPE_AGENT) < tB)
      __builtin_amdgcn_s_sleep(SLP);
  }
  asm volatile("" ::: "memory");
  __syncthreads();
}

__global__ void zero_sync(unsigned* p)
{
  for (int i = threadIdx.x; i < NSYNCW; i += 256) p[i] = 0u;
}

// ============================================================================
// Batched MFMA GEMM: C[M,N] = A[M,512] @ Bt[N,512]^T (+bias), fp32 out.
// (used for the xg0 pass)
// ============================================================================
__global__ __launch_bounds__(256) void gemm_bt(
    const bf16_t* __restrict__ A, const bf16_t* __restrict__ Bt,
    const float* __restrict__ bias, float* __restrict__ C,
    int Nvalid, int ldc, int permute_tb)
{
  const int bm = blockIdx.x * 128, bn = blockIdx.y * 128;
  const int tid = threadIdx.x;
  const int wave = tid >> 6, lane = tid & 63;
  const int wm = (wave >> 1) * 64, wn = (wave & 1) * 64;
  const int l15 = lane & 15, kg = lane >> 4;
  const bf16_t* Ap = A + (size_t)(bm + wm + l15) * 512 + kg * 8;
  const bf16_t* Bp = Bt + (size_t)(bn + wn + l15) * 512 + kg * 8;
  f32x4 acc[4][4];
#pragma unroll
  for (int i = 0; i < 4; ++i)
#pragma unroll
    for (int j = 0; j < 4; ++j)
#pragma unroll
      for (int e = 0; e < 4; ++e) acc[i][j][e] = 0.f;

  for (int kk = 0; kk < 512; kk += 32) {
    bf16x8 a[4], b[4];
#pragma unroll
    for (int i = 0; i < 4; ++i) a[i] = *(const bf16x8*)(Ap + (size_t)i * 16 * 512 + kk);
#pragma unroll
    for (int j = 0; j < 4; ++j) b[j] = *(const bf16x8*)(Bp + (size_t)j * 16 * 512 + kk);
#pragma unroll
    for (int i = 0; i < 4; ++i)
#pragma unroll
      for (int j = 0; j < 4; ++j)
        acc[i][j] = __builtin_amdgcn_mfma_f32_16x16x32_bf16(a[i], b[j], acc[i][j], 0, 0, 0);
  }

#pragma unroll
  for (int fm = 0; fm < 4; ++fm) {
#pragma unroll
    for (int fn = 0; fn < 4; ++fn) {
      int n = bn + wn + fn * 16 + l15;
      if (n >= Nvalid) continue;
      float bv = bias ? bias[n] : 0.f;
#pragma unroll
      for (int e = 0; e < 4; ++e) {
        int m = bm + wm + fm * 16 + kg * 4 + e;
        int orow = permute_tb ? ((m & 127) * TT + (m >> 7)) : m;
        C[(size_t)orow * ldc + n] = acc[fm][fn][e] + bv;
      }
    }
  }
}

// ============================================================================
// Dual-pipeline column-ownership persistent GRU + fused logits.
//   blocks [0,96):  half = bid/48, b2 = bid%48:
//     b2 in [0,16):  layer 0, owns H-cols [q*32, q*32+32), rows [half*64,+64)
//     b2 in [16,48): layer 1, owns H-cols [q*16, q*16+16), rows [half*64,+64)
//   blocks [96,256): logits workers (wait both halves' CHB1 counters)
// Per half: L0 s=0..39: [wait CHB0(h,s)=16] RU0 -> inc CRH0 ; wait CRH0=16 ;
//           C0 -> inc CHB0(h,s+1).  L1 s=1..40 analogous (targets 32).
// ============================================================================
struct PArgs {
  const bf16_t *Btru0, *Bt1ru, *Btc0, *Btc1;
  const float  *xg0, *bu, *br, *bc, *hs0init;
  bf16_t *hb0_seq, *hb1_seq, *rh0s, *rh1s;
  const bf16_t *Wto;
  const float  *bo;
  float *out, *out_hfin;
  unsigned *sync;
};

// 64-row GEMM: output 64 x (NF*16) over K; A panels (base already at the
// pipeline's row0) plain-cached; B swizzled in LDS (row stride 2*K bytes).
template<int K, int NF>
__device__ __forceinline__ void tile_gemm64(
    const bf16_t* __restrict__ A0, const bf16_t* __restrict__ A1,
    const bf16_t* Bs, int wave, int lane, f32x4 (&acc)[NF])
{
  const int l15 = lane & 15, kg = lane >> 4;
  const int mw = wave * 16;
#pragma unroll
  for (int f = 0; f < NF; ++f)
#pragma unroll
    for (int e = 0; e < 4; ++e) acc[f][e] = 0.f;

#pragma unroll
  for (int kk = 0; kk < K; kk += 32) {
    const bf16_t* Asrc = (kk < 512) ? A0 : A1;
    const int kc = (kk < 512 ? kk : kk - 512) + kg * 8;
    bf16x8 a = *(const bf16x8*)(Asrc + (size_t)(mw + l15) * 512 + kc);
    bf16x8 b[NF];
#pragma unroll
    for (int f = 0; f < NF; ++f) {
      int row = f * 16 + l15;
      int byteoff = row * (2 * K) + ((2 * kk + 16 * kg) ^ ((row & 7) << 4));
      b[f] = *(const bf16x8*)((const char*)Bs + byteoff);
    }
#pragma unroll
    for (int f = 0; f < NF; ++f)
      acc[f] = __builtin_amdgcn_mfma_f32_16x16x32_bf16(a, b[f], acc[f], 0, 0, 0);
  }
}

// Publish C cols (32/16) x 64 rows as bf16 into [128][512] slot at (row0,n0).
template<int C>
__device__ __forceinline__ void publish64(
    bf16_t* dst, int row0, int n0, float (&v)[2][4],
    unsigned short (*tb)[36], int wave, int lane, int tid)
{
  const int l15 = lane & 15, kg = lane >> 4;
  const int mw = wave * 16;
  constexpr int NFp = C / 16;
#pragma unroll
  for (int f = 0; f < NFp; ++f)
#pragma unroll
    for (int e = 0; e < 4; ++e)
      tb[mw + kg * 4 + e][f * 16 + l15] =
          __builtin_bit_cast(unsigned short, (bf16_t)v[f][e]);
  __syncthreads();
  constexpr int NU = 64 * C / 4;        // u64 stores
  constexpr int IT = (NU + 255) / 256;
#pragma unroll
  for (int it = 0; it < IT; ++it) {
    int lin = it * 256 + tid;
    if (lin < NU) {
      int row = lin / (C / 4);
      int cc  = (lin % (C / 4)) * 4;
      u16x4 pk = { tb[row][cc], tb[row][cc + 1], tb[row][cc + 2], tb[row][cc + 3] };
      cst64(dst + (size_t)(row0 + row) * 512 + n0 + cc, __builtin_bit_cast(u64, pk));
    }
  }
}

__global__ __launch_bounds__(256) void gru_persist(PArgs P)
{
  const int bid = blockIdx.x, tid = threadIdx.x;
  const int wave = tid >> 6, lane = tid & 63;
  const int l15 = lane & 15, kg = lane >> 4;
  unsigned* sync = P.sync;

  // One-time per-block L2/L1 invalidate (stale clean-line protocol, R12).
  __threadfence();
  __syncthreads();

  // ===================== logits worker blocks =====================
  if (bid >= NBLK) {
    const int w = bid - NBLK;                 // 0..159
    const int wm = (wave >> 1) * 64, wn = (wave & 1) * 64;
    for (int tau = w; tau < TT * 79; tau += (NGRID - NBLK)) {
      const int t = tau / 79, nb = tau % 79;
      slot_wait2<64>(sync, CHB1(0, t + 1), 32u, CHB1(1, t + 1), 32u);
      const bf16_t* A = P.hb1_seq + (size_t)(t + 1) * SLOT;
      const bf16_t* Bp = P.Wto + (size_t)(nb * 128 + wn + l15) * 512 + kg * 8;
      f32x4 acc[4][4];
#pragma unroll
      for (int i = 0; i < 4; ++i)
#pragma unroll
        for (int j = 0; j < 4; ++j)
#pragma unroll
          for (int e = 0; e < 4; ++e) acc[i][j][e] = 0.f;
      for (int kk = 0; kk < 512; kk += 32) {
        bf16x8 a[4], b[4];
#pragma unroll
        for (int i = 0; i < 4; ++i)
          a[i] = *(const bf16x8*)(A + (size_t)(wm + i * 16 + l15) * 512 + kk + kg * 8);
#pragma unroll
        for (int j = 0; j < 4; ++j)
          b[j] = *(const bf16x8*)(Bp + (size_t)j * 16 * 512 + kk);
#pragma unroll
        for (int i = 0; i < 4; ++i)
#pragma unroll
          for (int j = 0; j < 4; ++j)
            acc[i][j] = __builtin_amdgcn_mfma_f32_16x16x32_bf16(a[i], b[j], acc[i][j], 0, 0, 0);
      }
#pragma unroll
      for (int fm = 0; fm < 4; ++fm) {
#pragma unroll
        for (int fn = 0; fn < 4; ++fn) {
          int n = nb * 128 + wn + fn * 16 + l15;
          if (n >= VV) continue;
          float bv = P.bo[n];
#pragma unroll
          for (int e = 0; e < 4; ++e) {
            int b_row = wm + fm * 16 + kg * 4 + e;
            P.out[(size_t)(b_row * TT + t) * VV + n] = acc[fm][fn][e] + bv;
          }
        }
      }
      __syncthreads();
    }
    return;
  }

  // ===================== recurrence blocks ================================
  const int half = bid / 48;
  const int b2   = bid % 48;
  const int row0 = half * 64;
  const bool L0 = (b2 < 16);
  const int q  = L0 ? b2 : b2 - 16;
  const int n0 = L0 ? q * 32 : q * 16;
  const int mw = wave * 16;

  __shared__ bf16_t Bs[49152];                  // [RU 64KB | C 32KB]
  __shared__ unsigned short tb[64][36];
  bf16_t* BsRU = Bs;
  bf16_t* BsC  = Bs + 32768;

  if (L0) {
    for (int c = tid; c < 4096; c += 256) {
      int row = c >> 6, cb = (c & 63) * 16;
      const bf16_t* src = (row < 32) ? P.Btru0 + (size_t)(n0 + row) * 512
                                     : P.Btru0 + (size_t)(512 + n0 + row - 32) * 512;
      *(f4*)((char*)BsRU + row * 1024 + (cb ^ ((row & 7) << 4))) =
          *(const f4*)((const char*)src + cb);
    }
    for (int c = tid; c < 2048; c += 256) {
      int row = c >> 6, cb = (c & 63) * 16;
      const bf16_t* src = P.Btc0 + (size_t)(n0 + row) * 512;
      *(f4*)((char*)BsC + row * 1024 + (cb ^ ((row & 7) << 4))) =
          *(const f4*)((const char*)src + cb);
    }
  } else {
    for (int c = tid; c < 4096; c += 256) {
      int row = c >> 7, cb = (c & 127) * 16;
      const bf16_t* src = (row < 16) ? P.Bt1ru + (size_t)(n0 + row) * 1024
                                     : P.Bt1ru + (size_t)(512 + n0 + row - 16) * 1024;
      *(f4*)((char*)BsRU + row * 2048 + (cb ^ ((row & 7) << 4))) =
          *(const f4*)((const char*)src + cb);
    }
    for (int c = tid; c < 2048; c += 256) {
      int row = c >> 7, cb = (c & 127) * 16;
      const bf16_t* src = P.Btc1 + (size_t)(n0 + row) * 1024;
      *(f4*)((char*)BsC + row * 2048 + (cb ^ ((row & 7) << 4))) =
          *(const f4*)((const char*)src + cb);
    }
  }
  __syncthreads();

  const int NFh = L0 ? 2 : 1;
  float hreg[2][4], ureg[2][4], rhv[2][4];
#pragma unroll
  for (int f = 0; f < 2; ++f)
#pragma unroll
    for (int e = 0; e < 4; ++e) {
      int row = row0 + mw + kg * 4 + e;
      hreg[f][e] = (f < NFh)
          ? P.hs0init[(size_t)row * 512 + n0 + f * 16 + l15] : 0.f;
      ureg[f][e] = 0.f; rhv[f][e] = 0.f;
    }

  if (L0) {
    // ===================== layer-0 chain =====================
    for (int s = 0; s < 40; ++s) {
      if (s >= 1) slot_wait<8>(sync, CHB0(half, s), 16u);
      f32x4 acc4[4];
      const bf16_t* A0 = P.hb0_seq + (size_t)s * SLOT + (size_t)row0 * 512;
      tile_gemm64<512, 4>(A0, A0, BsRU, wave, lane, acc4);
      const float* xg = P.xg0 + (size_t)s * 128 * 1536;
#pragma unroll
      for (int f = 0; f < 2; ++f)
#pragma unroll
        for (int e = 0; e < 4; ++e) {
          int row = row0 + mw + kg * 4 + e;
          int col = n0 + f * 16 + l15;
          float pu = acc4[f][e]     + xg[(size_t)row * 1536 + col];
          float pr = acc4[f + 2][e] + xg[(size_t)row * 1536 + 512 + col];
          ureg[f][e] = 1.f / (1.f + expf(-pu));
          rhv[f][e]  = (1.f / (1.f + expf(-pr))) * hreg[f][e];
        }
      publish64<32>(P.rh0s + (size_t)s * SLOT, row0, n0, rhv, tb, wave, lane, tid);
      slot_inc(sync, CRH0(half, s));
      slot_wait<8>(sync, CRH0(half, s), 16u);

      f32x4 acc2[2];
      const bf16_t* Arh = P.rh0s + (size_t)s * SLOT + (size_t)row0 * 512;
      tile_gemm64<512, 2>(Arh, Arh, BsC, wave, lane, acc2);
#pragma unroll
      for (int f = 0; f < 2; ++f)
#pragma unroll
        for (int e = 0; e < 4; ++e) {
          int row = row0 + mw + kg * 4 + e;
          int col = n0 + f * 16 + l15;
          float c = tanhf(acc2[f][e] + xg[(size_t)row * 1536 + 1024 + col]);
          float u = ureg[f][e];
          hreg[f][e] = u * hreg[f][e] + (1.f - u) * c;
          rhv[f][e] = hreg[f][e];
        }
      publish64<32>(P.hb0_seq + (size_t)(s + 1) * SLOT, row0, n0, rhv, tb, wave, lane, tid);
      slot_inc(sync, CHB0(half, s + 1));
    }
  } else {
    // ===================== layer-1 chain =====================
    for (int s = 1; s <= 40; ++s) {
      if (s >= 2) slot_wait2<8>(sync, CHB0(half, s), 16u, CHB1(half, s - 1), 32u);
      else        slot_wait<8>(sync, CHB0(half, 1), 16u);
      f32x4 acc2[2];
      tile_gemm64<1024, 2>(P.hb0_seq + (size_t)s * SLOT + (size_t)row0 * 512,
                           P.hb1_seq + (size_t)(s - 1) * SLOT + (size_t)row0 * 512,
                           BsRU, wave, lane, acc2);
      float bvu = P.bu[512 + n0 + l15];
      float bvr = P.br[512 + n0 + l15];
#pragma unroll
      for (int e = 0; e < 4; ++e) {
        float pu = acc2[0][e] + bvu;
        float pr = acc2[1][e] + bvr;
        ureg[0][e] = 1.f / (1.f + expf(-pu));
        rhv[0][e]  = (1.f / (1.f + expf(-pr))) * hreg[0][e];
      }
      publish64<16>(P.rh1s + (size_t)s * SLOT, row0, n0, rhv, tb, wave, lane, tid);
      slot_inc(sync, CRH1(half, s));
      slot_wait<8>(sync, CRH1(half, s), 32u);

      f32x4 acc1[1];
      tile_gemm64<1024, 1>(P.hb0_seq + (size_t)s * SLOT + (size_t)row0 * 512,
                           P.rh1s + (size_t)s * SLOT + (size_t)row0 * 512,
                           BsC, wave, lane, acc1);
      float bvc = P.bc[512 + n0 + l15];
#pragma unroll
      for (int e = 0; e < 4; ++e) {
        float c = tanhf(acc1[0][e] + bvc);
        float u = ureg[0][e];
        hreg[0][e] = u * hreg[0][e] + (1.f - u) * c;
        rhv[0][e] = hreg[0][e];
      }
      publish64<16>(P.hb1_seq + (size_t)s * SLOT, row0, n0, rhv, tb, wave, lane, tid);
      slot_inc(sync, CHB1(half, s));
    }
  }

  // ---- h_final [L,B,H]: owner blocks write their fp32 slices ----
  float* dst = P.out_hfin + (L0 ? 0 : 65536);
#pragma unroll
  for (int f = 0; f < 2; ++f)
    if (f < NFh)
#pragma unroll
      for (int e = 0; e < 4; ++e) {
        int row = row0 + mw + kg * 4 + e;
        dst[(size_t)row * 512 + n0 + f * 16 + l15] = hreg[f][e];
      }
}

// ============================================================================
// h0 = tanh(vgg @ W_in + b_in) via bf16 MFMA, split-K=8.
// ============================================================================
__global__ __launch_bounds__(256) void h0_gemm(
    const bf16_t* __restrict__ vggb, const bf16_t* __restrict__ Wint,
    float* __restrict__ part)
{
  const int bn = blockIdx.x * 128, z = blockIdx.y, k0 = z * 512;
  const int tid = threadIdx.x;
  const int wave = tid >> 6, lane = tid & 63;
  const int wm = (wave >> 1) * 64, wn = (wave & 1) * 64;
  const int l15 = lane & 15, kg = lane >> 4;
  const bf16_t* Ap = vggb + (size_t)(wm + l15) * 4096 + k0 + kg * 8;
  const bf16_t* Bp = Wint + (size_t)(bn + wn + l15) * 4096 + k0 + kg * 8;
  f32x4 acc[4][4];
#pragma unroll
  for (int i = 0; i < 4; ++i)
#pragma unroll
    for (int j = 0; j < 4; ++j)
#pragma unroll
      for (int e = 0; e < 4; ++e) acc[i][j][e] = 0.f;
  for (int kk = 0; kk < 512; kk += 32) {
    bf16x8 a[4], b[4];
#pragma unroll
    for (int i = 0; i < 4; ++i) a[i] = *(const bf16x8*)(Ap + (size_t)i * 16 * 4096 + kk);
#pragma unroll
    for (int j = 0; j < 4; ++j) b[j] = *(const bf16x8*)(Bp + (size_t)j * 16 * 4096 + kk);
#pragma unroll
    for (int i = 0; i < 4; ++i)
#pragma unroll
      for (int j = 0; j < 4; ++j)
        acc[i][j] = __builtin_amdgcn_mfma_f32_16x16x32_bf16(a[i], b[j], acc[i][j], 0, 0, 0);
  }
#pragma unroll
  for (int fm = 0; fm < 4; ++fm)
#pragma unroll
    for (int fn = 0; fn < 4; ++fn) {
      int n = bn + wn + fn * 16 + l15;
#pragma unroll
      for (int e = 0; e < 4; ++e) {
        int m = wm + fm * 16 + kg * 4 + e;
        part[(size_t)z * SLOT + m * 512 + n] = acc[fm][fn][e];
      }
    }
}

__global__ void h0_fin(const float* __restrict__ part, const float* __restrict__ bin,
                       float* __restrict__ hs0init,
                       bf16_t* __restrict__ hb00, bf16_t* __restrict__ hb10)
{
  int i = blockIdx.x * 256 + threadIdx.x;   // 65536
  int n = i & 511;
  float s = bin[n];
#pragma unroll
  for (int z = 0; z < 8; ++z) s += part[(size_t)z * SLOT + i];
  float v = tanhf(s);
  hs0init[i] = v;
  hb00[i] = (bf16_t)v; hb10[i] = (bf16_t)v;
}

__global__ void conv_bf16(const float* __restrict__ src, bf16_t* __restrict__ dst)
{
  int i = blockIdx.x * 256 + threadIdx.x;
  f4 v = ((const f4*)src)[i];
  dst[i * 4 + 0] = (bf16_t)v[0]; dst[i * 4 + 1] = (bf16_t)v[1];
  dst[i * 4 + 2] = (bf16_t)v[2]; dst[i * 4 + 3] = (bf16_t)v[3];
}

__global__ void gather_emb(const int* __restrict__ tok, const float* __restrict__ emb,
                           bf16_t* __restrict__ A)
{
  int m = blockIdx.x;
  int t = m >> 7, b = m & 127;
  int tk = tok[b * TT + t];
  const float* src = emb + (size_t)tk * 512;
  int i = threadIdx.x;
  f4 v = *(const f4*)(src + i * 4);
  bf16_t* dst = A + (size_t)m * 512 + i * 4;
  dst[0] = (bf16_t)v[0]; dst[1] = (bf16_t)v[1];
  dst[2] = (bf16_t)v[2]; dst[3] = (bf16_t)v[3];
}

struct TJob { const float* src; bf16_t* dst; int K; int dstld; };
struct TJobs10 { TJob j[10]; };
__global__ void transpose_gen(TJobs10 jobs)
{
  TJob jb = jobs.j[blockIdx.z];
  int k0 = blockIdx.x * 32;
  if (k0 >= jb.K) return;
  int n0 = blockIdx.y * 32;
  __shared__ float tile[32][33];
  int tx = threadIdx.x, ty = threadIdx.y;
#pragma unroll
  for (int r = 0; r < 4; ++r)
    tile[ty + 8 * r][tx] = jb.src[(size_t)(k0 + ty + 8 * r) * 512 + n0 + tx];
  __syncthreads();
#pragma unroll
  for (int r = 0; r < 4; ++r)
    jb.dst[(size_t)(n0 + ty + 8 * r) * jb.dstld + k0 + tx] = (bf16_t)tile[tx][ty + 8 * r];
}

__global__ void transpose_wout(const float* __restrict__ W, bf16_t* __restrict__ dst)
{
  __shared__ float tile[32][33];
  int k0 = blockIdx.x * 32, n0 = blockIdx.y * 32;
  int tx = threadIdx.x, ty = threadIdx.y;
#pragma unroll
  for (int r = 0; r < 4; ++r) {
    int n = n0 + tx;
    tile[ty + 8 * r][tx] = (n < VV) ? W[(size_t)(k0 + ty + 8 * r) * VV + n] : 0.f;
  }
  __syncthreads();
#pragma unroll
  for (int r = 0; r < 4; ++r)
    dst[(size_t)(n0 + ty + 8 * r) * 512 + k0 + tx] = (bf16_t)tile[tx][ty + 8 * r];
}

__global__ void build_xbias(const float* __restrict__ bu, const float* __restrict__ br,
                            const float* __restrict__ bc, float* __restrict__ xb)
{
  int i = blockIdx.x * 256 + threadIdx.x;
  if (i < 2 * 1536) {
    int j = i / 1536, qq = i % 1536;
    int g = qq >> 9, n = qq & 511;
    const float* src = (g == 0) ? bu : (g == 1) ? br : bc;
    xb[i] = src[j * 512 + n];
  }
}

// ============================================================================
extern "C" void kernel_launch(void* const* d_in, const int* in_sizes, int n_in,
                              void* d_out, int out_size, void* d_ws, size_t ws_size,
                              hipStream_t stream)
{
  const int*   tok = (const int*)  d_in[0];
  const float* vgg = (const float*)d_in[1];
  const float* emb = (const float*)d_in[2];
  const float* Win = (const float*)d_in[3];
  const float* bin = (const float*)d_in[4];
  const float* Wu  = (const float*)d_in[5];
  const float* bu  = (const float*)d_in[6];
  const float* Wr  = (const float*)d_in[7];
  const float* br  = (const float*)d_in[8];
  const float* Wc  = (const float*)d_in[9];
  const float* bc  = (const float*)d_in[10];
  const float* Wo  = (const float*)d_in[11];
  const float* bo  = (const float*)d_in[12];
  float* out = (float*)d_out;

  size_t off = 0;
  auto alloc = [&](size_t bytes) -> void* {
    void* p = (char*)d_ws + off;
    off += (bytes + 255) & ~(size_t)255;
    return p;
  };
  float*  hs0init = (float*) alloc(SLOT * 4);
  bf16_t* rh0s  = (bf16_t*)alloc(41 * SLOT * 2);
  bf16_t* rh1s  = (bf16_t*)alloc(41 * SLOT * 2);
  bf16_t* hb0_seq = (bf16_t*)alloc(41 * SLOT * 2);
  bf16_t* hb1_seq = (bf16_t*)alloc(41 * SLOT * 2);
  bf16_t* Aemb  = (bf16_t*)alloc((size_t)TT * BB * 512 * 2);
  float*  xg0   = (float*) alloc((size_t)TT * BB * 1536 * 4);
  bf16_t* Btx0  = (bf16_t*)alloc((size_t)1536 * 512 * 2);
  bf16_t* Btru0 = (bf16_t*)alloc((size_t)1024 * 512 * 2);
  bf16_t* Btc0  = (bf16_t*)alloc((size_t)512 * 512 * 2);
  bf16_t* Bt1ru = (bf16_t*)alloc((size_t)1024 * 1024 * 2);
  bf16_t* Btc1  = (bf16_t*)alloc((size_t)512 * 1024 * 2);
  bf16_t* Wto   = (bf16_t*)alloc((size_t)10112 * 512 * 2);
  bf16_t* Wint  = (bf16_t*)alloc((size_t)512 * 4096 * 2);
  bf16_t* vggb  = (bf16_t*)alloc((size_t)128 * 4096 * 2);
  float*  h0part= (float*) alloc(8 * SLOT * 4);
  float*  xbias = (float*) alloc(2 * 1536 * 4);
  unsigned* syncws = (unsigned*) alloc(NSYNCW * 4);
  if (off > ws_size) return;

  TJobs10 tj;
  tj.j[0] = { Wu,                Btx0,                512, 512 };
  tj.j[1] = { Wr,                Btx0 + 262144,       512, 512 };
  tj.j[2] = { Wc,                Btx0 + 524288,       512, 512 };
  tj.j[3] = { Wu + 262144,       Btru0,               512, 512 };
  tj.j[4] = { Wr + 262144,       Btru0 + 262144,      512, 512 };
  tj.j[5] = { Wc + 262144,       Btc0,                512, 512 };
  tj.j[6] = { Wu + 524288,       Bt1ru,               1024, 1024 };
  tj.j[7] = { Wr + 524288,       Bt1ru + 524288,      1024, 1024 };
  tj.j[8] = { Wc + 524288,       Btc1,                1024, 1024 };
  tj.j[9] = { Win,               Wint,                4096, 4096 };
  transpose_gen<<<dim3(128, 16, 10), dim3(32, 8), 0, stream>>>(tj);
  transpose_wout<<<dim3(16, 316), dim3(32, 8), 0, stream>>>(Wo, Wto);
  build_xbias<<<12, 256, 0, stream>>>(bu, br, bc, xbias);
  gather_emb<<<TT * BB, 128, 0, stream>>>(tok, emb, Aemb);
  conv_bf16<<<512, 256, 0, stream>>>(vgg, vggb);
  zero_sync<<<1, 256, 0, stream>>>(syncws);

  h0_gemm<<<dim3(4, 8), 256, 0, stream>>>(vggb, Wint, h0part);
  h0_fin<<<256, 256, 0, stream>>>(h0part, bin, hs0init, hb0_seq, hb1_seq);

  gemm_bt<<<dim3(40, 12), 256, 0, stream>>>(Aemb, Btx0, xbias, xg0, 1536, 1536, 0);

  PArgs pa;
  pa.Btru0 = Btru0; pa.Bt1ru = Bt1ru; pa.Btc0 = Btc0; pa.Btc1 = Btc1;
  pa.xg0 = xg0; pa.bu = bu; pa.br = br; pa.bc = bc; pa.hs0init = hs0init;
  pa.hb0_seq = hb0_seq; pa.hb1_seq = hb1_seq;
  pa.rh0s = rh0s; pa.rh1s = rh1s;
  pa.Wto = Wto; pa.bo = bo; pa.out = out;
  pa.out_hfin = out + (size_t)BB * TT * VV;
  pa.sync = syncws;
  gru_persist<<<NGRID, 256, 0, stream>>>(pa);
}